// Round 9
// baseline (77.681 us; speedup 1.0000x reference)
//
#include <hip/hip_runtime.h>
#include <hip/hip_bf16.h>

#define NN 64
#define CC 3
#define LL 4096
#define SS 64
#define KK 128
#define WW 4033           // LL - SS + 1
#define BLKN 8            // blocks per n (each covers 512 windows)

typedef __attribute__((ext_vector_type(8))) short v8s;   // 8 bf16 MFMA A/B frag
typedef __attribute__((ext_vector_type(4))) float v4f;   // 4 fp32 MFMA C/D frag

// ---- ws layout (bytes) ----
// d2g:  u32[NN*KK]  @ 0       (32768)
// cnt:  u32[NN]     @ 32768   (256)
// hs2g: f32[CC*KK]  @ 33024   (1536)   -0.5*||s||^2
#define WS_CNT_OFF 32768
#define WS_HS2_OFF 33024

__device__ __forceinline__ unsigned bf16_rne(float f) {
    unsigned u = __float_as_uint(f);
    return (u + 0x7FFFu + ((u >> 16) & 1u)) >> 16;
}

// ---------------------------------------------------------------------------
// Init: 8 blocks x 256. d2g=+inf, cnt=0, hs2g=-0.5*||s||^2. Everything else
// (shapelet pack, x2 scan) moved into me_main blocks (self-sufficient).
__global__ __launch_bounds__(256) void me_init(
        const float* __restrict__ shp,
        unsigned* __restrict__ d2g,
        unsigned* __restrict__ cnt,
        float* __restrict__ hs2g) {
    int tid = blockIdx.x * 256 + threadIdx.x;      // 0..2047
    uint4 inf4 = {0x7F800000u, 0x7F800000u, 0x7F800000u, 0x7F800000u};
    ((uint4*)d2g)[tid] = inf4;                     // 2048*4 = 8192 words
    if (tid < NN) cnt[tid] = 0u;
    if (tid < CC * KK) {
        const float* r = shp + tid * SS;
        float a = 0.f;
        #pragma unroll 8
        for (int s = 0; s < SS; ++s) a += r[s] * r[s];
        hs2g[tid] = -0.5f * a;
    }
}

// ---------------------------------------------------------------------------
// Main: 512 blocks = (n, 512-window supertile). Self-sufficient:
//  A: all threads pack the full bf16 shapelet frag tile (shp -> LDS, 12
//     chunks/thread); waves 0-2 stage x (bf16 dual-copy) + prefix-scan x^2.
//  B: hx2s[c][w] = -0.5*(P[w+63]-P[w-1])  (-1e30 for w >= WW).
//  C: MFMA: wave = 128 windows (8 m-tiles) x 128 shapelets x K=64.
// acc init = -0.5*s2 (regs); epilogue adds -0.5*x2; min d2 = max(-2*maxD,0).
__global__ __launch_bounds__(256, 2) void me_main(
        const float* __restrict__ x,
        const float* __restrict__ shp,
        const float* __restrict__ hs2g,
        unsigned* __restrict__ d2g,
        unsigned* __restrict__ cnt,
        float* __restrict__ out) {

    __shared__ __align__(16) ushort shb[CC * 8192];   // 48 KB shapelet frags
    __shared__ __align__(8) ushort xs2[2][CC][640];   // [copy][c] bf16 x (575 used)
    __shared__ float Pp[CC][580];                     // prefix of x^2 (576 used)
    __shared__ float hx2s[CC][512];                   // -0.5*x2 (or -1e30)
    __shared__ unsigned red[KK];
    __shared__ int lastflag;

    const int b    = blockIdx.x;
    const int n    = b >> 3;          // BLKN=8 blocks per n
    const int tg   = b & 7;
    const int w0   = tg * 512;
    const int t    = threadIdx.x;
    const int lane = t & 63, wave = t >> 6;
    const int quad = lane >> 4, col = lane & 15;
    const int wbase = wave * 128;     // wave's window base within supertile

    if (t < KK) red[t] = 0x7F800000u;

    // ---- Phase A: pack shapelet frags shp -> shb (B-operand frag order:
    //      chunk ((c*8+nt)*2+sc)*64+l holds shp[c][nt*16+(l&15)][sc*32+(l>>4)*8+j])
    #pragma unroll
    for (int it = 0; it < 12; ++it) {
        int cidx = t + it * 256;           // 0..3071
        int c   = cidx >> 10;
        int r   = cidx & 1023;
        int nt  = r >> 7;
        int scb = (r >> 6) & 1;
        int l   = r & 63;
        int row  = nt * 16 + (l & 15);
        int koff = scb * 32 + (l >> 4) * 8;
        const float* s = shp + (size_t)(c * KK + row) * SS + koff;
        float4 f0 = *(const float4*)s;
        float4 f1 = *(const float4*)(s + 4);
        uint4 o;
        o.x = (bf16_rne(f0.y) << 16) | bf16_rne(f0.x);
        o.y = (bf16_rne(f0.w) << 16) | bf16_rne(f0.z);
        o.z = (bf16_rne(f1.y) << 16) | bf16_rne(f1.x);
        o.w = (bf16_rne(f1.w) << 16) | bf16_rne(f1.z);
        ((uint4*)shb)[cidx] = o;
    }

    // ---- -0.5*s2 into registers (indexed by this lane's col) ----
    float hsv[CC][8];
    #pragma unroll
    for (int c = 0; c < CC; ++c)
        #pragma unroll
        for (int nt = 0; nt < 8; ++nt)
            hsv[c][nt] = hs2g[c * KK + nt * 16 + col];

    const float* xb = x + (size_t)n * (CC * LL);

    // ---- Phase A' (waves 0-2): stage x bf16 dual-copy + prefix scan x^2 ----
    if (wave < 3) {
        const float* xc = xb + wave * LL;
        float carry = 0.f;
        #pragma unroll
        for (int seg = 0; seg < 9; ++seg) {
            int idx = seg * 64 + lane;       // 0..575
            int gi  = w0 + idx;
            float v = (gi < LL) ? xc[gi] : 0.f;
            ushort hv = (ushort)bf16_rne(v);
            xs2[0][wave][idx] = hv;
            if (idx > 0) xs2[1][wave][idx - 1] = hv;
            float sq = v * v;
            #pragma unroll
            for (int d = 1; d < 64; d <<= 1) {
                float u = __shfl_up(sq, d, 64);
                if (lane >= d) sq += u;
            }
            sq += carry;
            Pp[wave][idx] = sq;
            carry = __shfl(sq, 63, 64);
        }
    }
    __syncthreads();

    // ---- Phase B: hx2s from prefix table ----
    #pragma unroll
    for (int it = 0; it < 6; ++it) {
        int e = t + it * 256;                // 0..1535
        int c = e >> 9, w = e & 511;
        float I1 = Pp[c][w + 63];
        float I0 = (w > 0) ? Pp[c][w - 1] : 0.f;
        hx2s[c][w] = (w0 + w < WW) ? (-0.5f * (I1 - I0)) : -1e30f;
    }
    __syncthreads();

    // ---- Phase C: MFMA ----
    float rmax[8];
    #pragma unroll
    for (int nt = 0; nt < 8; ++nt) rmax[nt] = -3.4e38f;

    #pragma unroll
    for (int c = 0; c < CC; ++c) {
        // -0.5*x2 for this wave's 128 window rows (LDS b128 broadcast reads)
        v4f hxv[8];
        #pragma unroll
        for (int mt = 0; mt < 8; ++mt)
            hxv[mt] = *(const v4f*)(&hx2s[c][wbase + mt * 16 + quad * 4]);
        // A-frags: 8 m-tiles x 2 k-chunks, dual-copy dword-aligned reads
        v8s af[8][2];
        #pragma unroll
        for (int mt = 0; mt < 8; ++mt)
            #pragma unroll
            for (int sc = 0; sc < 2; ++sc) {
                int e0 = wbase + mt * 16 + col + sc * 32 + quad * 8;
                int p  = col & 1;
                const uint* ap = (const uint*)&xs2[p][c][e0 - p];
                union { v8s v; uint u[4]; } au;
                au.u[0] = ap[0]; au.u[1] = ap[1];
                au.u[2] = ap[2]; au.u[3] = ap[3];
                af[mt][sc] = au.v;
            }
        // 4 groups of 2 n-tiles to bound acc register pressure
        #pragma unroll
        for (int g = 0; g < 4; ++g) {
            v4f acc[2][8];   // [nt2][mt]
            #pragma unroll
            for (int nt2 = 0; nt2 < 2; ++nt2) {
                float h = hsv[c][g * 2 + nt2];
                v4f a = {h, h, h, h};
                #pragma unroll
                for (int mt = 0; mt < 8; ++mt) acc[nt2][mt] = a;
            }
            #pragma unroll
            for (int sc = 0; sc < 2; ++sc)
                #pragma unroll
                for (int nt2 = 0; nt2 < 2; ++nt2) {
                    int nt = g * 2 + nt2;
                    v8s bfr = *(const v8s*)(shb + (((c * 8 + nt) * 2 + sc) * 64 + lane) * 8);
                    #pragma unroll
                    for (int mt = 0; mt < 8; ++mt)
                        acc[nt2][mt] = __builtin_amdgcn_mfma_f32_16x16x32_bf16(
                            af[mt][sc], bfr, acc[nt2][mt], 0, 0, 0);
                }
            // epilogue: add -0.5*x2 rows, fold max over 32 window rows
            #pragma unroll
            for (int nt2 = 0; nt2 < 2; ++nt2) {
                float m = -3.4e38f;
                #pragma unroll
                for (int mt = 0; mt < 8; ++mt) {
                    v4f a = acc[nt2][mt];
                    #pragma unroll
                    for (int r = 0; r < 4; ++r)
                        m = fmaxf(m, a[r] + hxv[mt][r]);
                }
                rmax[g * 2 + nt2] = fmaxf(rmax[g * 2 + nt2], m);
            }
        }
    }

    // ---- reduce over quads (window rows live across quad+regs) ----
    #pragma unroll
    for (int nt = 0; nt < 8; ++nt) {
        float v = rmax[nt];
        v = fmaxf(v, __shfl_xor(v, 16, 64));
        v = fmaxf(v, __shfl_xor(v, 32, 64));
        rmax[nt] = v;
    }
    if (quad == 0) {
        #pragma unroll
        for (int nt = 0; nt < 8; ++nt) {
            float d2 = fmaxf(-2.f * rmax[nt], 0.f);
            atomicMin(&red[nt * 16 + col], __float_as_uint(d2));
        }
    }
    __syncthreads();
    if (t < KK) atomicMin(&d2g[n * KK + t], red[t]);   // device-scope RMW

    // ---- last block for this n writes sqrt -> out ----
    __syncthreads();   // vmcnt(0) drain: d2g mins globally done before cnt
    if (t == 0) {
        unsigned old = atomicAdd(&cnt[n], 1u);
        lastflag = (old == BLKN - 1) ? 1 : 0;
    }
    __syncthreads();
    if (lastflag && t < KK) {
        unsigned bits = atomicMin(&d2g[n * KK + t], 0x7F800000u);
        out[n * KK + t] = sqrtf(__uint_as_float(bits));
    }
}

// ---------------------------------------------------------------------------
extern "C" void kernel_launch(void* const* d_in, const int* in_sizes, int n_in,
                              void* d_out, int out_size, void* d_ws, size_t ws_size,
                              hipStream_t stream) {
    const float* x   = (const float*)d_in[0];   // (N, C, L) fp32
    const float* shp = (const float*)d_in[1];   // (C, K, S) fp32
    unsigned* d2g  = (unsigned*)d_ws;
    unsigned* cnt  = (unsigned*)((char*)d_ws + WS_CNT_OFF);
    float*    hs2g = (float*)((char*)d_ws + WS_HS2_OFF);
    float* out = (float*)d_out;

    hipLaunchKernelGGL(me_init, dim3(8), dim3(256), 0, stream, shp, d2g, cnt, hs2g);
    hipLaunchKernelGGL(me_main, dim3(NN * BLKN), dim3(256), 0, stream,
                       x, shp, hs2g, d2g, cnt, out);
}